// Round 4
// baseline (3088.181 us; speedup 1.0000x reference)
//
#include <hip/hip_runtime.h>
#include <stdint.h>
#include <stddef.h>

// Persistent 2-layer LSTM, V4: per-block flag barrier (no RMW serialization),
// direct global->register A-fragments (no h LDS staging), x prefetch under the
// poll, LDS pad to force 1 block/CU.
// B=128,T=512,D=128,H=512. 8 clusters x 32 blocks; block owns 16 h-cols of
// both layers; weights register-resident; 4 waves = 4 K-quarters.

typedef __attribute__((ext_vector_type(8))) short short8;
typedef __attribute__((ext_vector_type(4))) float f32x4;
typedef unsigned long long u64;

#define DEV static __device__ __forceinline__
#define SCOPE_AGENT __HIP_MEMORY_SCOPE_AGENT

constexpr int TSEQ = 512;
constexpr int DIN  = 128;
constexpr int HDIM = 512;
constexpr int NCL  = 8;    // clusters (bid&7 -> XCD heuristic; perf-only)
constexpr int BB   = 16;   // batch rows per cluster
constexpr int NJ   = 32;   // blocks per cluster
constexpr int COLS = 16;   // h-cols per block

DEV unsigned short f2bf(float f) {
  unsigned u = __float_as_uint(f);
  u += 0x7fffu + ((u >> 16) & 1u);   // RNE
  return (unsigned short)(u >> 16);
}
DEV short8 pack8(float4 a, float4 b) {
  short8 r;
  r[0] = (short)f2bf(a.x); r[1] = (short)f2bf(a.y);
  r[2] = (short)f2bf(a.z); r[3] = (short)f2bf(a.w);
  r[4] = (short)f2bf(b.x); r[5] = (short)f2bf(b.y);
  r[6] = (short)f2bf(b.z); r[7] = (short)f2bf(b.w);
  return r;
}
DEV short8 mk8(u64 lo, u64 hi) {
  union { u64 q[2]; short8 v; } u;
  u.q[0] = lo; u.q[1] = hi; return u.v;
}
DEV f32x4 mfma16(short8 a, short8 b, f32x4 c) {
  return __builtin_amdgcn_mfma_f32_16x16x32_bf16(a, b, c, 0, 0, 0);
}
DEV float sigf(float v) { return 1.f / (1.f + __expf(-v)); }
DEV float tanh_(float v) {
  v = fminf(20.f, fmaxf(-20.f, v));
  float e = __expf(2.f * v);
  return (e - 1.f) / (e + 1.f);
}

__global__ void zero_ws(unsigned* p, int n) {
  int i = blockIdx.x * 256 + threadIdx.x;
  if (i < n)
    __hip_atomic_store(p + i, 0u, __ATOMIC_RELAXED, SCOPE_AGENT);
}

__global__ __launch_bounds__(256, 1) void lstm_persist(
    const float* __restrict__ x,
    const float* __restrict__ Wih1, const float* __restrict__ Whh1,
    const float* __restrict__ bih1, const float* __restrict__ bhh1,
    const float* __restrict__ Wih2, const float* __restrict__ Whh2,
    const float* __restrict__ bih2, const float* __restrict__ bhh2,
    float* __restrict__ out,
    unsigned short* __restrict__ buf1,   // [2][NCL][BB][HDIM] bf16 (h1/out1)
    unsigned short* __restrict__ buf2,   // [2][NCL][BB][HDIM] bf16 (h2)
    unsigned* __restrict__ flags)        // [NCL][NJ] per-block step flags
{
  __shared__ float red1[4 * 16 * 66];
  __shared__ float red2[4 * 16 * 66];
  __shared__ float bias1s[64], bias2s[64];
  __shared__ char  pad[49152];   // force LDS > 80KB -> exactly 1 block/CU

  const int tid  = threadIdx.x;
  const int lane = tid & 63;
  const int lm   = lane & 15;   // A row (batch row) / C col index
  const int lq   = lane >> 4;   // k-octet / C row group
  const int kq   = tid >> 6;    // wave = K-quarter

  const int bid     = blockIdx.x;
  const int cluster = bid & 7;
  const int j       = bid >> 3;       // 0..31 col-group within cluster
  const int cb      = cluster * BB;   // global batch base

  if (j == 999) pad[tid] = (char)tid;   // unreachable; keeps pad allocated

  // ---- persistent register weights: B-fragments, n = lane&15 -> gate row ----
  short8 wf1[4][5];   // layer1: K=640 -> 20 K-steps, 5 per wave, x4 gates
  short8 wf2[4][8];   // layer2: K=1024 -> 32 K-steps, 8 per wave, x4 gates
  #pragma unroll
  for (int g = 0; g < 4; ++g) {
    const int gr = g * HDIM + j * COLS + lm;
    #pragma unroll
    for (int sl = 0; sl < 5; ++sl) {
      const int k0 = (kq * 5 + sl) * 32 + 8 * lq;          // 0..639
      const float* src = (k0 < DIN) ? (Wih1 + (size_t)gr * DIN + k0)
                                    : (Whh1 + (size_t)gr * HDIM + (k0 - DIN));
      wf1[g][sl] = pack8(*(const float4*)src, *(const float4*)(src + 4));
    }
    #pragma unroll
    for (int sl = 0; sl < 8; ++sl) {
      const int k0 = (kq * 8 + sl) * 32 + 8 * lq;          // 0..1023
      const float* src = (k0 < HDIM) ? (Wih2 + (size_t)gr * HDIM + k0)
                                     : (Whh2 + (size_t)gr * HDIM + (k0 - HDIM));
      wf2[g][sl] = pack8(*(const float4*)src, *(const float4*)(src + 4));
    }
  }
  if (tid < 64) {
    const int g = tid >> 4, nn = tid & 15;
    const int gr = g * HDIM + j * COLS + nn;
    bias1s[tid] = bih1[gr] + bhh1[gr];
    bias2s[tid] = bih2[gr] + bhh2[gr];
  }

  // pickup: thread = (batch row pm, col pnn); owns c1,c2 across all steps
  const int pm = tid >> 4, pnn = tid & 15;
  float c1 = 0.f, c2 = 0.f;

  for (int it = 0; it <= TSEQ; ++it) {
    const bool l1 = (it < TSEQ);
    const bool l2 = (it >= 1);

    // ---- x prefetch for wave 0 (read-only input; overlaps the poll) ----
    float4 xf[8];
    if (kq == 0 && l1) {
      const float* xp = x + ((size_t)(cb + lm) * TSEQ + it) * DIN + 8 * lq;
      #pragma unroll
      for (int s = 0; s < 4; ++s) {
        xf[2 * s]     = *(const float4*)(xp + s * 32);
        xf[2 * s + 1] = *(const float4*)(xp + s * 32 + 4);
      }
    }

    // ---- barrier: every wave polls all 32 per-block flags in parallel ----
    if (it > 0) {
      const unsigned* fl = flags + cluster * NJ + (lane & 31);
      while (true) {
        unsigned v = __hip_atomic_load(fl, __ATOMIC_RELAXED, SCOPE_AGENT);
        if (__all((int)(v >= (unsigned)it))) break;
        __builtin_amdgcn_s_sleep(1);
      }
    }

    const unsigned short* h1r =
        buf1 + (size_t)(((it + 1) & 1) * NCL + cluster) * BB * HDIM;  // h1_{it-1}
    const unsigned short* h2r =
        buf2 + (size_t)((it & 1) * NCL + cluster) * BB * HDIM;        // h2_{it-2}

    // ---- direct global->register A-fragments (L1-bypassing 8B atomics) ----
    short8 a1[5], a2[8];
    if (l1) {
      #pragma unroll
      for (int sl = 0; sl < 5; ++sl) {
        const int s = kq * 5 + sl;            // K = [x(4) | h1(16)]
        if (kq == 0 && sl < 4) {
          a1[sl] = pack8(xf[2 * sl], xf[2 * sl + 1]);
        } else {
          const u64* p = (const u64*)(h1r + (size_t)lm * HDIM + (s - 4) * 32 + 8 * lq);
          a1[sl] = mk8(__hip_atomic_load(p,     __ATOMIC_RELAXED, SCOPE_AGENT),
                       __hip_atomic_load(p + 1, __ATOMIC_RELAXED, SCOPE_AGENT));
        }
      }
    }
    if (l2) {
      #pragma unroll
      for (int sl = 0; sl < 8; ++sl) {
        const int s2 = kq * 8 + sl;           // K = [out1(16) | h2(16)]
        const unsigned short* base = (s2 < 16) ? h1r : h2r;
        const int col = ((s2 < 16) ? s2 : (s2 - 16)) * 32 + 8 * lq;
        const u64* p = (const u64*)(base + (size_t)lm * HDIM + col);
        a2[sl] = mk8(__hip_atomic_load(p,     __ATOMIC_RELAXED, SCOPE_AGENT),
                     __hip_atomic_load(p + 1, __ATOMIC_RELAXED, SCOPE_AGENT));
      }
    }

    // ---- MFMA: wave kq does its K-quarter, all 4 gate N-tiles ----
    f32x4 z = {0.f, 0.f, 0.f, 0.f};
    f32x4 acc1[4] = {z, z, z, z};
    f32x4 acc2[4] = {z, z, z, z};
    if (l1) {
      #pragma unroll
      for (int sl = 0; sl < 5; ++sl)
        #pragma unroll
        for (int g = 0; g < 4; ++g) acc1[g] = mfma16(a1[sl], wf1[g][sl], acc1[g]);
    }
    if (l2) {
      #pragma unroll
      for (int sl = 0; sl < 8; ++sl)
        #pragma unroll
        for (int g = 0; g < 4; ++g) acc2[g] = mfma16(a2[sl], wf2[g][sl], acc2[g]);
    }

    // C layout: col = lane&15 (gate row), row = lq*4+r (batch row)
    if (l1) {
      #pragma unroll
      for (int g = 0; g < 4; ++g)
        #pragma unroll
        for (int r = 0; r < 4; ++r)
          red1[(kq * 16 + lq * 4 + r) * 66 + g * 16 + lm] = acc1[g][r];
    }
    if (l2) {
      #pragma unroll
      for (int g = 0; g < 4; ++g)
        #pragma unroll
        for (int r = 0; r < 4; ++r)
          red2[(kq * 16 + lq * 4 + r) * 66 + g * 16 + lm] = acc2[g][r];
    }
    __syncthreads();

    // ---- pickup: K-quarter reduce + gates + state + publish ----
    if (l1) {
      float p[4];
      #pragma unroll
      for (int g = 0; g < 4; ++g) {
        float v = bias1s[g * 16 + pnn];
        #pragma unroll
        for (int q = 0; q < 4; ++q) v += red1[(q * 16 + pm) * 66 + g * 16 + pnn];
        p[g] = v;
      }
      const float i_ = sigf(p[0]), f_ = sigf(p[1]);
      const float g_ = tanh_(p[2]), o_ = sigf(p[3]);
      c1 = f_ * c1 + i_ * g_;
      const float h1v = o_ * tanh_(c1);
      unsigned short* w = buf1 + (size_t)((it & 1) * NCL + cluster) * BB * HDIM;
      __hip_atomic_store(&w[pm * HDIM + j * COLS + pnn], f2bf(h1v),
                         __ATOMIC_RELAXED, SCOPE_AGENT);
    }
    if (l2) {
      float p[4];
      #pragma unroll
      for (int g = 0; g < 4; ++g) {
        float v = bias2s[g * 16 + pnn];
        #pragma unroll
        for (int q = 0; q < 4; ++q) v += red2[(q * 16 + pm) * 66 + g * 16 + pnn];
        p[g] = v;
      }
      const float i_ = sigf(p[0]), f_ = sigf(p[1]);
      const float g_ = tanh_(p[2]), o_ = sigf(p[3]);
      c2 = f_ * c2 + i_ * g_;
      const float h2v = o_ * tanh_(c2);
      if (l1) {
        unsigned short* w =
            buf2 + (size_t)(((it + 1) & 1) * NCL + cluster) * BB * HDIM;
        __hip_atomic_store(&w[pm * HDIM + j * COLS + pnn], f2bf(h2v),
                           __ATOMIC_RELAXED, SCOPE_AGENT);
      } else {
        const int b = cb + pm;                       // final states (t = 511)
        out[(size_t)b * HDIM + j * COLS + pnn] = h2v;
        out[(size_t)128 * HDIM + (size_t)b * HDIM + j * COLS + pnn] = c2;
      }
    }
    __syncthreads();   // hipcc drains vmcnt per-wave before s_barrier

    // ---- signal: one flag store per block (no RMW serialization) ----
    if (tid == 0 && l1)
      __hip_atomic_store(flags + cluster * NJ + j, (unsigned)(it + 1),
                         __ATOMIC_RELAXED, SCOPE_AGENT);
  }
}

extern "C" void kernel_launch(void* const* d_in, const int* in_sizes, int n_in,
                              void* d_out, int out_size, void* d_ws, size_t ws_size,
                              hipStream_t stream) {
  const float* x    = (const float*)d_in[0];
  const float* Wih1 = (const float*)d_in[1];
  const float* Whh1 = (const float*)d_in[2];
  const float* bih1 = (const float*)d_in[3];
  const float* bhh1 = (const float*)d_in[4];
  const float* Wih2 = (const float*)d_in[5];
  const float* Whh2 = (const float*)d_in[6];
  const float* bih2 = (const float*)d_in[7];
  const float* bhh2 = (const float*)d_in[8];
  float* out = (float*)d_out;

  const size_t bufElems = (size_t)2 * NCL * BB * HDIM;   // 131072 ushorts each
  unsigned short* buf1 = (unsigned short*)d_ws;
  unsigned short* buf2 = buf1 + bufElems;
  unsigned* flags = (unsigned*)(buf2 + bufElems);

  const int nzero = (int)((bufElems * 2 * 2 + NCL * NJ * 4) / 4);   // u32 words
  zero_ws<<<(nzero + 255) / 256, 256, 0, stream>>>((unsigned*)d_ws, nzero);
  lstm_persist<<<256, 256, 0, stream>>>(x, Wih1, Whh1, bih1, bhh1,
                                        Wih2, Whh2, bih2, bhh2,
                                        out, buf1, buf2, flags);
}